// Round 2
// baseline (672.348 us; speedup 1.0000x reference)
//
#include <hip/hip_runtime.h>
#include <hip/hip_cooperative_groups.h>

namespace cg = cooperative_groups;

// MPDNN SchNet-style MPNN, single cooperative mega-kernel.
//  - Wf(d) -> 4096-row fp32 lookup table (2 MB, L2-resident)
//  - compact neighbor lists (d<6, ~23% dense), entry = j | (table_row<<7)
//  - h and pre_j stored packed bf16 by the producer phase (halves staging)
//  - c_aniso.sum(j) pushed through @We2; c_iso/pre fused into conv-3 phase
//  - 4 grid.sync()s replace 5 kernel-boundary waits
// Fallback: if cooperative launch is rejected, run the proven 6-kernel path.

#define LN2F 0.69314718055994531f

__device__ __forceinline__ float sspf(float x) {          // softplus(x) - ln2, stable
  float e = __expf(-fabsf(x));
  return fmaxf(x, 0.0f) + __logf(1.0f + e) - LN2F;
}
__device__ __forceinline__ unsigned int f2bf(float x) {   // fp32 -> bf16 bits (RNE)
  unsigned int u = __float_as_uint(x);
  return (u + 0x7fffu + ((u >> 16) & 1u)) >> 16;
}
__device__ __forceinline__ float bflo(unsigned int u) { return __uint_as_float(u << 16); }
__device__ __forceinline__ float bfhi(unsigned int u) { return __uint_as_float(u & 0xffff0000u); }

struct Params {
  const float* coords; const int* species; const float* emb;
  const float* Wc1; const float* bc1; const float* Wc2; const float* bc2;
  const float* Wu1; const float* bu1; const float* Wu2; const float* bu2;
  const float* Wp1; const float* bp1; const float* Wp2; const float* bp2;
  const float* Wei; const float* Wej; const float* be1; const float* We2; const float* be2;
  float* out;
  float* table; float* h_a; float* h_b; float* pre_i;
  unsigned int* hbf_a; unsigned int* hbf_b; unsigned int* prejbf;
  unsigned int* ent; int* cnt;
};

union Smem {
  struct { unsigned int hsh[8192]; unsigned int ent[4][128]; float mred[8][128];
           float m[4][128]; float red[4][4][128]; float u1[4][128]; int nn[4]; } cv;
  struct { unsigned int pjs[8192]; unsigned int ent[4][128]; float pis[4][128];
           float sred[8][128]; float ss[4][128]; float r2[4][8][16]; int nn[4]; } ep;
  struct { float rbf[8][32]; float hid[8][128]; } tb;
  struct { int wc[8]; } nb;
};

// conv phase: message (table-gather over neighbor list) + update net, 4 nodes/block.
// keep=true leaves the final h of the block's 4 nodes in sm.cv.u1 for the pool phase.
__device__ __forceinline__ void conv_phase(Smem& sm, const Params& p, int t, int node0, int b,
    const float* __restrict__ hin, const unsigned int* __restrict__ hbfin,
    float* __restrict__ hout, unsigned int* __restrict__ hbfout, bool keep) {
  const unsigned int* hb = hbfin + b * 8192;
  for (int c = 0; c < 16; c++) sm.cv.hsh[c*512 + t] = hb[c*512 + t];
  { int ii = t >> 7, f = t & 127;
    sm.cv.ent[ii][f] = p.ent[(node0 + ii)*128 + f]; }
  if (t < 4) sm.cv.nn[t] = p.cnt[node0 + t];
  __syncthreads();

  int w = t >> 6, lane = t & 63;
  int ii = w >> 1, par = w & 1;
  int nnp = sm.cv.nn[ii] >> 16;                 // padded count (multiple of 4)
  float a0 = 0.f, a1 = 0.f, c0 = 0.f, c1 = 0.f;
  for (int e = par; e + 2 < nnp; e += 4) {
    unsigned int u0 = sm.cv.ent[ii][e], u1 = sm.cv.ent[ii][e + 2];
    int j0 = u0 & 127, k0 = (int)(u0 >> 7);
    int j1 = u1 & 127, k1 = (int)(u1 >> 7);
    float2 t0 = *(const float2*)(p.table + k0*128 + 2*lane);
    float2 t1 = *(const float2*)(p.table + k1*128 + 2*lane);
    unsigned int h0 = sm.cv.hsh[j0*64 + lane];
    unsigned int h1 = sm.cv.hsh[j1*64 + lane];
    a0 += t0.x * bflo(h0); a1 += t0.y * bfhi(h0);
    c0 += t1.x * bflo(h1); c1 += t1.y * bfhi(h1);
  }
  a0 += c0; a1 += c1;
  *(float2*)&sm.cv.mred[w][2*lane] = make_float2(a0, a1);
  __syncthreads();
  { int i2 = t >> 7, f = t & 127;
    sm.cv.m[i2][f] = sm.cv.mred[2*i2][f] + sm.cv.mred[2*i2+1][f]; }
  __syncthreads();

  int g = t & 127, q = t >> 7;
  {
    float p0=0,p1=0,p2=0,p3=0;
    for (int f = q*32; f < q*32 + 32; f++) {
      float wv = p.Wu1[f*128 + g];
      p0 += sm.cv.m[0][f]*wv; p1 += sm.cv.m[1][f]*wv;
      p2 += sm.cv.m[2][f]*wv; p3 += sm.cv.m[3][f]*wv;
    }
    sm.cv.red[q][0][g]=p0; sm.cv.red[q][1][g]=p1; sm.cv.red[q][2][g]=p2; sm.cv.red[q][3][g]=p3;
  }
  __syncthreads();
  { int i2 = t >> 7, gg = t & 127;
    sm.cv.u1[i2][gg] = sspf(sm.cv.red[0][i2][gg]+sm.cv.red[1][i2][gg]
                           +sm.cv.red[2][i2][gg]+sm.cv.red[3][i2][gg] + p.bu1[gg]); }
  __syncthreads();
  {
    float p0=0,p1=0,p2=0,p3=0;
    for (int f = q*32; f < q*32 + 32; f++) {
      float wv = p.Wu2[f*128 + g];
      p0 += sm.cv.u1[0][f]*wv; p1 += sm.cv.u1[1][f]*wv;
      p2 += sm.cv.u1[2][f]*wv; p3 += sm.cv.u1[3][f]*wv;
    }
    sm.cv.red[q][0][g]=p0; sm.cv.red[q][1][g]=p1; sm.cv.red[q][2][g]=p2; sm.cv.red[q][3][g]=p3;
  }
  __syncthreads();
  { int i2 = t >> 7, o = t & 127;
    int node = node0 + i2;
    float delta = sm.cv.red[0][i2][o]+sm.cv.red[1][i2][o]
                 +sm.cv.red[2][i2][o]+sm.cv.red[3][i2][o] + p.bu2[o];
    float hf = hin[node*128 + o] + delta;
    hout[node*128 + o] = hf;
    unsigned int lo = f2bf(hf);
    unsigned int hi = (unsigned int)__shfl_xor((int)lo, 1);
    if ((o & 1) == 0) hbfout[node*64 + (o >> 1)] = lo | (hi << 16);
    if (keep) sm.cv.u1[i2][o] = hf;     // u1 is dead here (red consumed it); safe overwrite
  }
}

__global__ __launch_bounds__(512, 4) void mega_kernel(Params p) {
  __shared__ Smem sm;
  cg::grid_group grid = cg::this_grid();
  const int t = threadIdx.x;
  const int blk = blockIdx.x;
  const int node0 = blk * 4;
  const int b = blk >> 5;

  // ---------------- P0a: neighbor lists + embedding ----------------
  {
    int ii = t >> 7, j = t & 127;
    int node = node0 + ii;
    int i = node & 127;
    const float* cb = p.coords + (b << 7) * 3;
    float cix = cb[i*3], ciy = cb[i*3+1], ciz = cb[i*3+2];
    float dx = cix - cb[j*3+0], dy = ciy - cb[j*3+1], dz = ciz - cb[j*3+2];
    float d = sqrtf(dx*dx + dy*dy + dz*dz);
    bool valid = (d < 6.0f) && (j != i);
    int k = 4096;                                   // 4096 = zero row (pad)
    if (valid) { k = (int)(d * (4096.0f/6.0f)); if (k > 4095) k = 4095; }
    unsigned long long bal = __ballot(valid);
    int lane = t & 63, w = t >> 6;
    if (lane == 0) sm.nb.wc[w] = (int)__popcll(bal);
    __syncthreads();
    int nn = sm.nb.wc[2*ii] + sm.nb.wc[2*ii+1];
    int base = ((w & 1) ? sm.nb.wc[w-1] : 0) + (int)__popcll(bal & ((1ull << lane) - 1ull));
    if (valid) p.ent[node*128 + base] = (unsigned int)(j | (k << 7));
    int nnp = (nn + 3) & ~3;
    if (j >= nn && j < nnp) p.ent[node*128 + j] = (4096u << 7);
    if (j == 0) p.cnt[node] = nn | (nnp << 16);
    float hv = p.emb[p.species[node]*128 + j];
    p.h_a[node*128 + j] = hv;
    unsigned int lo = f2bf(hv);
    unsigned int hi = (unsigned int)__shfl_xor((int)lo, 1);
    if ((j & 1) == 0) p.hbf_a[node*64 + (j >> 1)] = lo | (hi << 16);
    __syncthreads();
  }
  // ---------------- P0b: filter table, 8 rows/block ----------------
  {
    int t0 = blk * 8;
    for (int idx = t; idx < 256; idx += 512) {
      int tt = idx >> 5, kk = idx & 31;
      float d = (float)(t0 + tt) * (6.0f/4096.0f) + 0.5f * (6.0f/4096.0f);
      float mu = 0.5f + (float)kk * (5.5f/31.0f);
      float z = d - mu;
      sm.tb.rbf[tt][kk] = __expf(-8.0f * z * z);    // 1/(2*0.25^2)=8
    }
    __syncthreads();
    int f = t & 127, sub = t >> 7;
    int r0 = sub*2, r1 = r0 + 1;
    float s0 = p.bc1[f], s1 = s0;
    for (int kk = 0; kk < 32; kk++) {
      float wv = p.Wc1[kk*128 + f];
      s0 += sm.tb.rbf[r0][kk]*wv; s1 += sm.tb.rbf[r1][kk]*wv;
    }
    sm.tb.hid[r0][f] = sspf(s0); sm.tb.hid[r1][f] = sspf(s1);
    __syncthreads();
    float o0 = p.bc2[f], o1 = o0;
    for (int g = 0; g < 128; g++) {
      float wv = p.Wc2[g*128 + f];
      o0 += sm.tb.hid[r0][g]*wv; o1 += sm.tb.hid[r1][g]*wv;
    }
    p.table[(t0+r0)*128 + f] = o0;
    p.table[(t0+r1)*128 + f] = o1;
    if (blk == 0 && t < 128) p.table[4096*128 + t] = 0.0f;
  }
  __threadfence(); grid.sync();
  // ---------------- P1..P3: convolutions ----------------
  conv_phase(sm, p, t, node0, b, p.h_a, p.hbf_a, p.h_b, p.hbf_b, false);
  __threadfence(); grid.sync();
  conv_phase(sm, p, t, node0, b, p.h_b, p.hbf_b, p.h_a, p.hbf_a, false);
  __threadfence(); grid.sync();
  conv_phase(sm, p, t, node0, b, p.h_a, p.hbf_a, p.h_b, p.hbf_b, true);
  __syncthreads();
  // ---------------- P4: c_iso + pre_i / pre_j (block's own 4 nodes) ----------------
  {
    float (*hs)[128] = sm.cv.u1;
    float (*redp)[4][64] = reinterpret_cast<float (*)[4][64]>(sm.cv.red);
    float (*us)[64]      = reinterpret_cast<float (*)[64]>(sm.cv.m);
    int g = t & 63, q = t >> 6;                 // q in 0..7 -> 16-wide f segment
    float p0=0,p1=0,p2=0,p3=0;
    for (int f = q*16; f < q*16 + 16; f++) {
      float wv = p.Wp1[f*64 + g];
      p0 += hs[0][f]*wv; p1 += hs[1][f]*wv; p2 += hs[2][f]*wv; p3 += hs[3][f]*wv;
    }
    redp[q][0][g]=p0; redp[q][1][g]=p1; redp[q][2][g]=p2; redp[q][3][g]=p3;
    __syncthreads();
    if (t < 256) {
      int ii = t >> 6, gg = t & 63;
      float s = p.bp1[gg];
      for (int q2 = 0; q2 < 8; q2++) s += redp[q2][ii][gg];
      us[ii][gg] = sspf(s);
    }
    __syncthreads();
    if (t < 32) {
      int ii = t >> 3, o = t & 7;
      float v = p.bp2[o];
      for (int gg = 0; gg < 64; gg++) v += us[ii][gg] * p.Wp2[gg*8 + o];
      p.out[(node0 + ii)*8 + o] = v;
    }
    int o = t & 127, sel = (t >> 7) & 1, duo = t >> 8;
    const float* W = sel ? p.Wej : p.Wei;
    float q0 = 0.f, q1 = 0.f;
    for (int f = 0; f < 128; f++) {
      float wv = W[f*128 + o];
      q0 += hs[2*duo][f]*wv; q1 += hs[2*duo+1][f]*wv;
    }
    if (sel == 0) {
      p.pre_i[(node0 + 2*duo)*128 + o]     = q0;
      p.pre_i[(node0 + 2*duo + 1)*128 + o] = q1;
    } else {
      unsigned int l0 = f2bf(q0), l1 = f2bf(q1);
      unsigned int h0 = (unsigned int)__shfl_xor((int)l0, 1);
      unsigned int h1 = (unsigned int)__shfl_xor((int)l1, 1);
      if ((o & 1) == 0) {
        p.prejbf[(node0 + 2*duo)*64 + (o >> 1)]     = l0 | (h0 << 16);
        p.prejbf[(node0 + 2*duo + 1)*64 + (o >> 1)] = l1 | (h1 << 16);
      }
    }
  }
  __threadfence(); grid.sync();
  // ---------------- P5: edge pool ----------------
  {
    const unsigned int* pjb = p.prejbf + b * 8192;
    for (int c = 0; c < 16; c++) sm.ep.pjs[c*512 + t] = pjb[c*512 + t];
    { int ii = t >> 7, f = t & 127;
      sm.ep.pis[ii][f] = p.pre_i[(node0 + ii)*128 + f] + p.be1[f];
      sm.ep.ent[ii][f] = p.ent[(node0 + ii)*128 + f]; }
    if (t < 4) sm.ep.nn[t] = p.cnt[node0 + t] & 0xffff;
    __syncthreads();
    int w = t >> 6, lane = t & 63;
    int ii = w >> 1, par = w & 1;
    float pia = sm.ep.pis[ii][2*lane];
    float pib = sm.ep.pis[ii][2*lane + 1];
    int nn = sm.ep.nn[ii];
    float a0 = 0.f, a1 = 0.f;
    for (int e = par; e < nn; e += 2) {
      unsigned int u = sm.ep.ent[ii][e];
      int j = u & 127;
      unsigned int hv = sm.ep.pjs[j*64 + lane];
      a0 += sspf(pia + bflo(hv));
      a1 += sspf(pib + bfhi(hv));
    }
    *(float2*)&sm.ep.sred[w][2*lane] = make_float2(a0, a1);
    __syncthreads();
    { int i2 = t >> 7, f = t & 127;
      sm.ep.ss[i2][f] = sm.ep.sred[2*i2][f] + sm.ep.sred[2*i2+1][f]; }
    __syncthreads();
    { int i2 = t >> 7, o = t & 15, seg = (t >> 4) & 7;
      float pv = 0.f;
      for (int f = seg*16; f < seg*16 + 16; f++) pv += sm.ep.ss[i2][f] * p.We2[f*16 + o];
      sm.ep.r2[i2][seg][o] = pv; }
    __syncthreads();
    if (t < 64) {
      int i2 = t >> 4, o = t & 15;
      float v = p.be2[o] * (float)sm.ep.nn[i2];
      for (int s2 = 0; s2 < 8; s2++) v += sm.ep.r2[i2][s2][o];
      p.out[16384 + (node0 + i2)*16 + o] = v;
    }
  }
}

// ======================= fallback: proven 6-kernel path =======================

__global__ __launch_bounds__(256) void prep_kernel(
    const float* __restrict__ coords, const int* __restrict__ species,
    const float* __restrict__ emb,
    const float* __restrict__ Wc1, const float* __restrict__ bc1,
    const float* __restrict__ Wc2, const float* __restrict__ bc2,
    float* __restrict__ table, float* __restrict__ h_a,
    unsigned int* __restrict__ ent, int* __restrict__ cnt) {
  int t = threadIdx.x;
  if (blockIdx.x < 1024) {
    __shared__ int wc[4];
    int node = blockIdx.x * 2 + (t >> 7);
    int j = t & 127;
    int b = node >> 7, i = node & 127;
    float cix = coords[node*3+0], ciy = coords[node*3+1], ciz = coords[node*3+2];
    int jn = b*128 + j;
    float dx = cix - coords[jn*3+0];
    float dy = ciy - coords[jn*3+1];
    float dz = ciz - coords[jn*3+2];
    float d  = sqrtf(dx*dx + dy*dy + dz*dz);
    bool valid = (d < 6.0f) && (j != i);
    int k = 4096;
    if (valid) { k = (int)(d * (4096.0f/6.0f)); if (k > 4095) k = 4095; }
    unsigned long long bal = __ballot(valid);
    int lane = t & 63, w = t >> 6;
    if (lane == 0) wc[w] = (int)__popcll(bal);
    __syncthreads();
    int nloc = t >> 7;
    int nn = wc[2*nloc] + wc[2*nloc+1];
    int base = ((w & 1) ? wc[w-1] : 0) + (int)__popcll(bal & ((1ull << lane) - 1ull));
    if (valid) ent[node*128 + base] = (unsigned int)(j | (k << 7));
    int nnp = (nn + 3) & ~3;
    if (j >= nn && j < nnp) ent[node*128 + j] = (4096u << 7);
    if (j == 0) cnt[node] = nn | (nnp << 16);
    h_a[node*128 + j] = emb[species[node]*128 + j];
  } else {
    __shared__ float rbf_all[16][32];
    __shared__ float hid_all[16][128];
    int tb = (int)blockIdx.x - 1024;
    int t0 = tb * 16;
    for (int idx = t; idx < 512; idx += 256) {
      int tt = idx >> 5, kk = idx & 31;
      float d = (float)(t0 + tt) * (6.0f/4096.0f) + 0.5f * (6.0f/4096.0f);
      float mu = 0.5f + (float)kk * (5.5f/31.0f);
      float z = d - mu;
      rbf_all[tt][kk] = __expf(-8.0f * z * z);
    }
    __syncthreads();
    int f = t & 127, sub = t >> 7;
    float s[8];
    float b1 = bc1[f];
#pragma unroll
    for (int r = 0; r < 8; r++) s[r] = b1;
    for (int kk = 0; kk < 32; kk++) {
      float wv = Wc1[kk*128 + f];
#pragma unroll
      for (int r = 0; r < 8; r++) s[r] += rbf_all[sub*8 + r][kk] * wv;
    }
#pragma unroll
    for (int r = 0; r < 8; r++) hid_all[sub*8 + r][f] = sspf(s[r]);
    __syncthreads();
    float o[8];
    float b2 = bc2[f];
#pragma unroll
    for (int r = 0; r < 8; r++) o[r] = b2;
    for (int g = 0; g < 128; g++) {
      float wv = Wc2[g*128 + f];
#pragma unroll
      for (int r = 0; r < 8; r++) o[r] += hid_all[sub*8 + r][g] * wv;
    }
#pragma unroll
    for (int r = 0; r < 8; r++) table[(t0 + sub*8 + r)*128 + f] = o[r];
    if (tb == 255 && t < 128) table[4096*128 + t] = 0.0f;
  }
}

__global__ __launch_bounds__(512) void conv_kernel(
    const float* __restrict__ h_cur, float* __restrict__ h_next,
    const float* __restrict__ table, const unsigned int* __restrict__ ent,
    const int* __restrict__ cnt,
    const float* __restrict__ Wu1, const float* __restrict__ bu1,
    const float* __restrict__ Wu2, const float* __restrict__ bu2) {
  __shared__ unsigned int hsh[8192];
  __shared__ unsigned int ent_s[4][128];
  __shared__ float mred[8][128];
  __shared__ float m_s[4][128];
  __shared__ float red[4][4][128];
  __shared__ float u1_s[4][128];
  __shared__ int nn_s[4];
  int t = threadIdx.x;
  int node0 = blockIdx.x * 4;
  int b = blockIdx.x >> 5;
  const float2* hb = (const float2*)(h_cur + b*16384);
  for (int c = 0; c < 16; c++) {
    int idx = c*512 + t;
    float2 v = hb[idx];
    hsh[idx] = (f2bf(v.y) << 16) | f2bf(v.x);
  }
  { int ii = t >> 7, f = t & 127;
    ent_s[ii][f] = ent[(node0 + ii)*128 + f]; }
  if (t < 4) nn_s[t] = cnt[node0 + t];
  __syncthreads();
  int w = t >> 6, lane = t & 63;
  int ii = w >> 1, par = w & 1;
  int nnp = nn_s[ii] >> 16;
  float a0 = 0.f, a1 = 0.f, c0 = 0.f, c1 = 0.f;
  for (int e = par; e + 2 < nnp; e += 4) {
    unsigned int u0 = ent_s[ii][e], u1 = ent_s[ii][e + 2];
    int j0 = u0 & 127, k0 = (int)(u0 >> 7);
    int j1 = u1 & 127, k1 = (int)(u1 >> 7);
    float2 t0 = *(const float2*)(table + k0*128 + 2*lane);
    float2 t1 = *(const float2*)(table + k1*128 + 2*lane);
    unsigned int h0 = hsh[j0*64 + lane];
    unsigned int h1 = hsh[j1*64 + lane];
    a0 += t0.x * bflo(h0); a1 += t0.y * bfhi(h0);
    c0 += t1.x * bflo(h1); c1 += t1.y * bfhi(h1);
  }
  a0 += c0; a1 += c1;
  *(float2*)&mred[w][2*lane] = make_float2(a0, a1);
  __syncthreads();
  { int i2 = t >> 7, f = t & 127;
    m_s[i2][f] = mred[2*i2][f] + mred[2*i2+1][f]; }
  __syncthreads();
  int g = t & 127, q = t >> 7;
  {
    float p0=0,p1=0,p2=0,p3=0;
    for (int f = q*32; f < q*32 + 32; f++) {
      float wv = Wu1[f*128 + g];
      p0 += m_s[0][f]*wv; p1 += m_s[1][f]*wv; p2 += m_s[2][f]*wv; p3 += m_s[3][f]*wv;
    }
    red[q][0][g]=p0; red[q][1][g]=p1; red[q][2][g]=p2; red[q][3][g]=p3;
  }
  __syncthreads();
  { int i2 = t >> 7, gg = t & 127;
    u1_s[i2][gg] = sspf(red[0][i2][gg]+red[1][i2][gg]+red[2][i2][gg]+red[3][i2][gg] + bu1[gg]); }
  __syncthreads();
  {
    float p0=0,p1=0,p2=0,p3=0;
    for (int f = q*32; f < q*32 + 32; f++) {
      float wv = Wu2[f*128 + g];
      p0 += u1_s[0][f]*wv; p1 += u1_s[1][f]*wv; p2 += u1_s[2][f]*wv; p3 += u1_s[3][f]*wv;
    }
    red[q][0][g]=p0; red[q][1][g]=p1; red[q][2][g]=p2; red[q][3][g]=p3;
  }
  __syncthreads();
  { int i2 = t >> 7, o = t & 127;
    int node = node0 + i2;
    float delta = red[0][i2][o]+red[1][i2][o]+red[2][i2][o]+red[3][i2][o] + bu2[o];
    h_next[node*128 + o] = h_cur[node*128 + o] + delta; }
}

__global__ __launch_bounds__(256) void poolpre_kernel(
    const float* __restrict__ h,
    const float* __restrict__ Wp1, const float* __restrict__ bp1,
    const float* __restrict__ Wp2, const float* __restrict__ bp2,
    const float* __restrict__ Wei, const float* __restrict__ Wej,
    float* __restrict__ pre_i, float* __restrict__ pre_j,
    float* __restrict__ out) {
  int t = threadIdx.x;
  if (blockIdx.x < 512) {
    __shared__ float hs[4][128];
    __shared__ float redp[4][4][64];
    __shared__ float us[4][64];
    int node0 = blockIdx.x * 4;
    for (int idx = t; idx < 512; idx += 256) hs[idx >> 7][idx & 127] = h[node0*128 + idx];
    __syncthreads();
    int g = t & 63, q = t >> 6;
    float p0=0,p1=0,p2=0,p3=0;
    for (int f = q*32; f < q*32 + 32; f++) {
      float wv = Wp1[f*64 + g];
      p0 += hs[0][f]*wv; p1 += hs[1][f]*wv; p2 += hs[2][f]*wv; p3 += hs[3][f]*wv;
    }
    redp[q][0][g]=p0; redp[q][1][g]=p1; redp[q][2][g]=p2; redp[q][3][g]=p3;
    __syncthreads();
    { int ii = t >> 6, gg = t & 63;
      us[ii][gg] = sspf(redp[0][ii][gg]+redp[1][ii][gg]+redp[2][ii][gg]+redp[3][ii][gg] + bp1[gg]); }
    __syncthreads();
    if (t < 32) {
      int ii = t >> 3, o = t & 7;
      float v = bp2[o];
      for (int gg = 0; gg < 64; gg++) v += us[ii][gg] * Wp2[gg*8 + o];
      out[(node0 + ii)*8 + o] = v;
    }
  } else {
    __shared__ float hs8[8][128];
    int node0 = ((int)blockIdx.x - 512) * 8;
    for (int idx = t; idx < 1024; idx += 256) hs8[idx >> 7][idx & 127] = h[node0*128 + idx];
    __syncthreads();
    int o = t & 127, which = t >> 7;
    const float* W = which ? Wej : Wei;
    float p0=0,p1=0,p2=0,p3=0,p4=0,p5=0,p6=0,p7=0;
    for (int f = 0; f < 128; f++) {
      float wv = W[f*128 + o];
      p0 += hs8[0][f]*wv; p1 += hs8[1][f]*wv; p2 += hs8[2][f]*wv; p3 += hs8[3][f]*wv;
      p4 += hs8[4][f]*wv; p5 += hs8[5][f]*wv; p6 += hs8[6][f]*wv; p7 += hs8[7][f]*wv;
    }
    float* dst = which ? pre_j : pre_i;
    dst[(node0+0)*128+o]=p0; dst[(node0+1)*128+o]=p1; dst[(node0+2)*128+o]=p2; dst[(node0+3)*128+o]=p3;
    dst[(node0+4)*128+o]=p4; dst[(node0+5)*128+o]=p5; dst[(node0+6)*128+o]=p6; dst[(node0+7)*128+o]=p7;
  }
}

__global__ __launch_bounds__(512) void edgepool_kernel(
    const float* __restrict__ pre_i, const float* __restrict__ pre_j,
    const unsigned int* __restrict__ ent, const int* __restrict__ cnt,
    const float* __restrict__ be1, const float* __restrict__ We2,
    const float* __restrict__ be2, float* __restrict__ out) {
  __shared__ unsigned int pjs[8192];
  __shared__ unsigned int ent_s[4][128];
  __shared__ float pis[4][128];
  __shared__ float sred[8][128];
  __shared__ float s_s[4][128];
  __shared__ float r2[4][8][16];
  __shared__ int nn_s[4];
  int t = threadIdx.x;
  int node0 = blockIdx.x * 4;
  int b = blockIdx.x >> 5;
  const float2* pjb = (const float2*)(pre_j + b*16384);
  for (int c = 0; c < 16; c++) {
    int idx = c*512 + t;
    float2 v = pjb[idx];
    pjs[idx] = (f2bf(v.y) << 16) | f2bf(v.x);
  }
  { int ii = t >> 7, f = t & 127;
    pis[ii][f] = pre_i[(node0 + ii)*128 + f];
    ent_s[ii][f] = ent[(node0 + ii)*128 + f]; }
  if (t < 4) nn_s[t] = cnt[node0 + t] & 0xffff;
  __syncthreads();
  int w = t >> 6, lane = t & 63;
  int ii = w >> 1, par = w & 1;
  float pia = pis[ii][2*lane]     + be1[2*lane];
  float pib = pis[ii][2*lane + 1] + be1[2*lane + 1];
  float a0 = 0.f, a1 = 0.f;
  int nn = nn_s[ii];
  for (int e = par; e < nn; e += 2) {
    unsigned int u = ent_s[ii][e];
    int j = u & 127;
    unsigned int hv = pjs[j*64 + lane];
    a0 += sspf(pia + bflo(hv));
    a1 += sspf(pib + bfhi(hv));
  }
  *(float2*)&sred[w][2*lane] = make_float2(a0, a1);
  __syncthreads();
  { int i2 = t >> 7, f = t & 127;
    s_s[i2][f] = sred[2*i2][f] + sred[2*i2+1][f]; }
  __syncthreads();
  { int i2 = t >> 7, o = t & 15, seg = (t >> 4) & 7;
    float p = 0.f;
    for (int f = seg*16; f < seg*16 + 16; f++) p += s_s[i2][f] * We2[f*16 + o];
    r2[i2][seg][o] = p; }
  __syncthreads();
  if (t < 64) {
    int i2 = t >> 4, o = t & 15;
    float v = be2[o] * (float)nn_s[i2];
    for (int seg = 0; seg < 8; seg++) v += r2[i2][seg][o];
    out[(node0 + i2)*16 + o] = v;
  }
}

// ---------------------------------------------------------------------------
extern "C" void kernel_launch(void* const* d_in, const int* in_sizes, int n_in,
                              void* d_out, int out_size, void* d_ws, size_t ws_size,
                              hipStream_t stream) {
  const float* coords = (const float*)d_in[0];
  const int*   species= (const int*)  d_in[1];
  const float* emb    = (const float*)d_in[2];
  const float* Wc1    = (const float*)d_in[3];
  const float* bc1    = (const float*)d_in[4];
  const float* Wc2    = (const float*)d_in[5];
  const float* bc2    = (const float*)d_in[6];
  const float* Wu1    = (const float*)d_in[7];
  const float* bu1    = (const float*)d_in[8];
  const float* Wu2    = (const float*)d_in[9];
  const float* bu2    = (const float*)d_in[10];
  const float* Wp1    = (const float*)d_in[11];
  const float* bp1    = (const float*)d_in[12];
  const float* Wp2    = (const float*)d_in[13];
  const float* bp2    = (const float*)d_in[14];
  const float* Wei    = (const float*)d_in[15];
  const float* Wej    = (const float*)d_in[16];
  const float* be1    = (const float*)d_in[17];
  const float* We2    = (const float*)d_in[18];
  const float* be2    = (const float*)d_in[19];
  float* out = (float*)d_out;

  float* wsf = (float*)d_ws;
  float*        table  = wsf;                                //  524,416
  float*        h_a    = wsf + 524416;                       //  262,144
  float*        h_b    = wsf + 786560;                       //  262,144
  float*        pre_i  = wsf + 1048704;                      //  262,144
  float*        pre_jf = wsf + 1310848;                      //  262,144 (fallback fp32)
  unsigned int* hbf_a  = (unsigned int*)(wsf + 1310848);     //  131,072 (mega)
  unsigned int* hbf_b  = hbf_a + 131072;                     //  131,072 (mega)
  unsigned int* prejbf = (unsigned int*)(wsf + 1572992);     //  131,072
  unsigned int* ent    = (unsigned int*)(wsf + 1704064);     //  262,144
  int*          cnt    = (int*)(wsf + 1966208);              //  2,048
  (void)in_sizes; (void)n_in; (void)out_size; (void)ws_size;

  Params prm;
  prm.coords = coords; prm.species = species; prm.emb = emb;
  prm.Wc1 = Wc1; prm.bc1 = bc1; prm.Wc2 = Wc2; prm.bc2 = bc2;
  prm.Wu1 = Wu1; prm.bu1 = bu1; prm.Wu2 = Wu2; prm.bu2 = bu2;
  prm.Wp1 = Wp1; prm.bp1 = bp1; prm.Wp2 = Wp2; prm.bp2 = bp2;
  prm.Wei = Wei; prm.Wej = Wej; prm.be1 = be1; prm.We2 = We2; prm.be2 = be2;
  prm.out = out;
  prm.table = table; prm.h_a = h_a; prm.h_b = h_b; prm.pre_i = pre_i;
  prm.hbf_a = hbf_a; prm.hbf_b = hbf_b; prm.prejbf = prejbf;
  prm.ent = ent; prm.cnt = cnt;

  void* kp[] = { &prm };
  hipError_t err = hipLaunchCooperativeKernel((const void*)mega_kernel,
                                              dim3(512), dim3(512), kp, 0, stream);
  if (err != hipSuccess) {
    // fallback: proven 6-kernel pipeline
    prep_kernel<<<1280, 256, 0, stream>>>(coords, species, emb, Wc1, bc1, Wc2, bc2,
                                          table, h_a, ent, cnt);
    conv_kernel<<<512, 512, 0, stream>>>(h_a, h_b, table, ent, cnt, Wu1, bu1, Wu2, bu2);
    conv_kernel<<<512, 512, 0, stream>>>(h_b, h_a, table, ent, cnt, Wu1, bu1, Wu2, bu2);
    conv_kernel<<<512, 512, 0, stream>>>(h_a, h_b, table, ent, cnt, Wu1, bu1, Wu2, bu2);
    poolpre_kernel<<<768, 256, 0, stream>>>(h_b, Wp1, bp1, Wp2, bp2, Wei, Wej,
                                            pre_i, pre_jf, out);
    edgepool_kernel<<<512, 512, 0, stream>>>(pre_i, pre_jf, ent, cnt, be1, We2, be2,
                                             out + 16384);
  }
}

// Round 3
// 60.054 us; speedup vs baseline: 11.1957x; 11.1957x over previous
//
#include <hip/hip_runtime.h>

// MPDNN SchNet-style MPNN, 5-dispatch pipeline (cooperative mega-kernel removed:
// grid.sync on gfx950 forces whole-L2 writeback/invalidate across non-coherent
// XCD L2s -> 233MB HBM traffic, 669us. Measured R2.)
//  - Wf(d) -> 4096-row fp32 lookup table (2 MB, L2-resident)
//  - compact neighbor lists (d<6, ~23% dense), entry = j | (table_row<<7)
//  - h kept as fp32 (residual path) + producer-packed bf16 (message staging)
//  - conv1 reads emb[species] directly (no h materialization pass)
//  - conv3 fuses NodePool (c_iso) + edge pre_i/pre_j; skips dead h writes
//  - c_aniso.sum(j) pushed through @We2
// ws (floats): table[4097*128] | h_a | h_b | pre_i | hbf_a | hbf_b | prejbf | ent | cnt

#define LN2F 0.69314718055994531f

__device__ __forceinline__ float sspf(float x) {          // softplus(x) - ln2, stable
  float e = __expf(-fabsf(x));
  return fmaxf(x, 0.0f) + __logf(1.0f + e) - LN2F;
}
__device__ __forceinline__ unsigned int f2bf(float x) {   // fp32 -> bf16 bits (RNE)
  unsigned int u = __float_as_uint(x);
  return (u + 0x7fffu + ((u >> 16) & 1u)) >> 16;
}
__device__ __forceinline__ float bflo(unsigned int u) { return __uint_as_float(u << 16); }
__device__ __forceinline__ float bfhi(unsigned int u) { return __uint_as_float(u & 0xffff0000u); }

// ---------------------------------------------------------------------------
// prep: blocks [0,1024): neighbor lists (2 nodes/block)
//       blocks [1024,1536): filter table, 8 d-samples/block
// ---------------------------------------------------------------------------
__global__ __launch_bounds__(256) void prep_kernel(
    const float* __restrict__ coords,
    const float* __restrict__ Wc1, const float* __restrict__ bc1,
    const float* __restrict__ Wc2, const float* __restrict__ bc2,
    float* __restrict__ table,
    unsigned int* __restrict__ ent, int* __restrict__ cnt) {
  int t = threadIdx.x;
  if (blockIdx.x < 1024) {
    __shared__ int wc[4];
    int node = blockIdx.x * 2 + (t >> 7);
    int j = t & 127;
    int b = node >> 7, i = node & 127;
    const float* cb = coords + (b << 7) * 3;
    float dx = cb[i*3+0] - cb[j*3+0];
    float dy = cb[i*3+1] - cb[j*3+1];
    float dz = cb[i*3+2] - cb[j*3+2];
    float d  = sqrtf(dx*dx + dy*dy + dz*dz);
    bool valid = (d < 6.0f) && (j != i);
    int k = 4096;                                   // 4096 = zero row (pad)
    if (valid) { k = (int)(d * (4096.0f/6.0f)); if (k > 4095) k = 4095; }
    unsigned long long bal = __ballot(valid);
    int lane = t & 63, w = t >> 6;
    if (lane == 0) wc[w] = (int)__popcll(bal);
    __syncthreads();
    int ii = t >> 7;
    int nn = wc[2*ii] + wc[2*ii+1];
    int base = ((w & 1) ? wc[w-1] : 0) + (int)__popcll(bal & ((1ull << lane) - 1ull));
    if (valid) ent[node*128 + base] = (unsigned int)(j | (k << 7));
    int nnp = (nn + 3) & ~3;
    if (j >= nn && j < nnp) ent[node*128 + j] = (4096u << 7);
    if (j == 0) cnt[node] = nn | (nnp << 16);
  } else {
    __shared__ float rbf[8][32];
    __shared__ float hid[8][128];
    int tb = (int)blockIdx.x - 1024;                // 0..511
    int t0 = tb * 8;
    { int tt = t >> 5, kk = t & 31;                 // 256 threads = 8x32 exactly
      float d = (float)(t0 + tt) * (6.0f/4096.0f) + 0.5f * (6.0f/4096.0f);
      float mu = 0.5f + (float)kk * (5.5f/31.0f);
      float z = d - mu;
      rbf[tt][kk] = __expf(-8.0f * z * z); }        // 1/(2*0.25^2)=8
    __syncthreads();
    int f = t & 127, sub = t >> 7;                  // sub in 0..1 -> rows sub*4..+3
    float s0 = bc1[f], s1 = s0, s2 = s0, s3 = s0;
    int r0 = sub * 4;
    for (int kk = 0; kk < 32; kk++) {
      float wv = Wc1[kk*128 + f];
      s0 += rbf[r0+0][kk]*wv; s1 += rbf[r0+1][kk]*wv;
      s2 += rbf[r0+2][kk]*wv; s3 += rbf[r0+3][kk]*wv;
    }
    hid[r0+0][f] = sspf(s0); hid[r0+1][f] = sspf(s1);
    hid[r0+2][f] = sspf(s2); hid[r0+3][f] = sspf(s3);
    __syncthreads();
    float o0 = bc2[f], o1 = o0, o2 = o0, o3 = o0;
    for (int g = 0; g < 128; g++) {
      float wv = Wc2[g*128 + f];
      o0 += hid[r0+0][g]*wv; o1 += hid[r0+1][g]*wv;
      o2 += hid[r0+2][g]*wv; o3 += hid[r0+3][g]*wv;
    }
    table[(t0+r0+0)*128 + f] = o0;
    table[(t0+r0+1)*128 + f] = o1;
    table[(t0+r0+2)*128 + f] = o2;
    table[(t0+r0+3)*128 + f] = o3;
    if (tb == 0 && t < 128) table[4096*128 + t] = 0.0f;
  }
}

// ---------------------------------------------------------------------------
// conv: one block = 4 nodes. message (table-gather) + update net.
// SRC_EMB: h_in is emb[species] computed on the fly (conv 1).
// LAST:    skip h stores; fuse NodePool (c_iso) + pre_i/pre_j (conv 3).
// ---------------------------------------------------------------------------
template<bool SRC_EMB, bool LAST>
__global__ __launch_bounds__(512) void conv_t(
    const float* __restrict__ h_in, const unsigned int* __restrict__ hbf_in,
    float* __restrict__ h_out, unsigned int* __restrict__ hbf_out,
    const int* __restrict__ species, const float* __restrict__ emb,
    const float* __restrict__ table, const unsigned int* __restrict__ ent,
    const int* __restrict__ cnt,
    const float* __restrict__ Wu1, const float* __restrict__ bu1,
    const float* __restrict__ Wu2, const float* __restrict__ bu2,
    const float* __restrict__ Wp1, const float* __restrict__ bp1,
    const float* __restrict__ Wp2, const float* __restrict__ bp2,
    const float* __restrict__ Wei, const float* __restrict__ Wej,
    float* __restrict__ pre_i, unsigned int* __restrict__ prejbf,
    float* __restrict__ out) {
  __shared__ unsigned int hsh[8192];        // h[b] as bf16x2, 32 KB
  __shared__ unsigned int ent_s[4][128];
  __shared__ float mred[8][128];
  __shared__ float m_s[4][128];
  __shared__ float red[4][4][128];
  __shared__ float u1_s[4][128];
  __shared__ int nn_s[4];
  int t = threadIdx.x;
  int node0 = blockIdx.x * 4;
  int b = blockIdx.x >> 5;

  if constexpr (SRC_EMB) {
    const int* spb = species + (b << 7);
    for (int c = 0; c < 16; c++) {
      int idx = c*512 + t;
      int j = idx >> 6, f2 = idx & 63;
      float2 v = *(const float2*)(emb + spb[j]*128 + 2*f2);
      hsh[idx] = (f2bf(v.y) << 16) | f2bf(v.x);
    }
  } else {
    const unsigned int* hb = hbf_in + b * 8192;
    for (int c = 0; c < 16; c++) hsh[c*512 + t] = hb[c*512 + t];
  }
  { int ii = t >> 7, f = t & 127;
    ent_s[ii][f] = ent[(node0 + ii)*128 + f]; }
  if (t < 4) nn_s[t] = cnt[node0 + t];
  __syncthreads();

  // --- message: wave pair strides the neighbor list, 2-way unrolled ---
  int w = t >> 6, lane = t & 63;
  int ii = w >> 1, par = w & 1;
  int nnp = nn_s[ii] >> 16;                 // padded count (multiple of 4)
  float a0 = 0.f, a1 = 0.f, c0 = 0.f, c1 = 0.f;
  for (int e = par; e + 2 < nnp; e += 4) {
    unsigned int u0 = ent_s[ii][e], u1 = ent_s[ii][e + 2];
    int j0 = u0 & 127, k0 = (int)(u0 >> 7);
    int j1 = u1 & 127, k1 = (int)(u1 >> 7);
    float2 t0 = *(const float2*)(table + k0*128 + 2*lane);
    float2 t1 = *(const float2*)(table + k1*128 + 2*lane);
    unsigned int h0 = hsh[j0*64 + lane];
    unsigned int h1 = hsh[j1*64 + lane];
    a0 += t0.x * bflo(h0); a1 += t0.y * bfhi(h0);
    c0 += t1.x * bflo(h1); c1 += t1.y * bfhi(h1);
  }
  a0 += c0; a1 += c1;
  *(float2*)&mred[w][2*lane] = make_float2(a0, a1);
  __syncthreads();
  { int i2 = t >> 7, f = t & 127;
    m_s[i2][f] = mred[2*i2][f] + mred[2*i2+1][f]; }
  __syncthreads();

  // --- update net, 4 rows batched per weight load ---
  int g = t & 127, q = t >> 7;
  {
    float p0=0,p1=0,p2=0,p3=0;
    for (int f = q*32; f < q*32 + 32; f++) {
      float wv = Wu1[f*128 + g];
      p0 += m_s[0][f]*wv; p1 += m_s[1][f]*wv; p2 += m_s[2][f]*wv; p3 += m_s[3][f]*wv;
    }
    red[q][0][g]=p0; red[q][1][g]=p1; red[q][2][g]=p2; red[q][3][g]=p3;
  }
  __syncthreads();
  { int i2 = t >> 7, gg = t & 127;
    u1_s[i2][gg] = sspf(red[0][i2][gg]+red[1][i2][gg]+red[2][i2][gg]+red[3][i2][gg] + bu1[gg]); }
  __syncthreads();
  {
    float p0=0,p1=0,p2=0,p3=0;
    for (int f = q*32; f < q*32 + 32; f++) {
      float wv = Wu2[f*128 + g];
      p0 += u1_s[0][f]*wv; p1 += u1_s[1][f]*wv; p2 += u1_s[2][f]*wv; p3 += u1_s[3][f]*wv;
    }
    red[q][0][g]=p0; red[q][1][g]=p1; red[q][2][g]=p2; red[q][3][g]=p3;
  }
  __syncthreads();
  { int i2 = t >> 7, o = t & 127;
    int node = node0 + i2;
    float delta = red[0][i2][o]+red[1][i2][o]+red[2][i2][o]+red[3][i2][o] + bu2[o];
    float base;
    if constexpr (SRC_EMB) base = emb[species[node]*128 + o];
    else                   base = h_in[node*128 + o];
    float hf = base + delta;
    if constexpr (!LAST) {
      h_out[node*128 + o] = hf;
      unsigned int lo = f2bf(hf);
      unsigned int hi = (unsigned int)__shfl_xor((int)lo, 1);
      if ((o & 1) == 0) hbf_out[node*64 + (o >> 1)] = lo | (hi << 16);
    } else {
      u1_s[i2][o] = hf;                     // u1 dead here; keep h for pools
    }
  }
  if constexpr (LAST) {
    __syncthreads();
    float (*hs)[128]     = u1_s;
    float (*redp)[4][64] = reinterpret_cast<float (*)[4][64]>(red);
    float (*us)[64]      = reinterpret_cast<float (*)[64]>(m_s);
    int gp = t & 63, qp = t >> 6;           // qp 0..7 -> 16-wide f segment
    float p0=0,p1=0,p2=0,p3=0;
    for (int f = qp*16; f < qp*16 + 16; f++) {
      float wv = Wp1[f*64 + gp];
      p0 += hs[0][f]*wv; p1 += hs[1][f]*wv; p2 += hs[2][f]*wv; p3 += hs[3][f]*wv;
    }
    redp[qp][0][gp]=p0; redp[qp][1][gp]=p1; redp[qp][2][gp]=p2; redp[qp][3][gp]=p3;
    __syncthreads();
    if (t < 256) {
      int i4 = t >> 6, gg = t & 63;
      float s = bp1[gg];
      for (int q2 = 0; q2 < 8; q2++) s += redp[q2][i4][gg];
      us[i4][gg] = sspf(s);
    }
    __syncthreads();
    if (t < 32) {
      int i4 = t >> 3, o = t & 7;
      float v = bp2[o];
      for (int gg = 0; gg < 64; gg++) v += us[i4][gg] * Wp2[gg*8 + o];
      out[(node0 + i4)*8 + o] = v;
    }
    int o = t & 127, sel = (t >> 7) & 1, duo = t >> 8;
    const float* W = sel ? Wej : Wei;
    float q0 = 0.f, q1 = 0.f;
    for (int f = 0; f < 128; f++) {
      float wv = W[f*128 + o];
      q0 += hs[2*duo][f]*wv; q1 += hs[2*duo+1][f]*wv;
    }
    if (sel == 0) {
      pre_i[(node0 + 2*duo)*128 + o]     = q0;
      pre_i[(node0 + 2*duo + 1)*128 + o] = q1;
    } else {
      unsigned int l0 = f2bf(q0), l1 = f2bf(q1);
      unsigned int h0 = (unsigned int)__shfl_xor((int)l0, 1);
      unsigned int h1 = (unsigned int)__shfl_xor((int)l1, 1);
      if ((o & 1) == 0) {
        prejbf[(node0 + 2*duo)*64 + (o >> 1)]     = l0 | (h0 << 16);
        prejbf[(node0 + 2*duo + 1)*64 + (o >> 1)] = l1 | (h1 << 16);
      }
    }
  }
}

// ---------------------------------------------------------------------------
// edgepool: c_aniso_sum[node] = (sum_j ssp(pre_i+be1+pre_j)) @ We2 + be2*nn
// ---------------------------------------------------------------------------
__global__ __launch_bounds__(512) void edgepool_kernel(
    const float* __restrict__ pre_i, const unsigned int* __restrict__ prejbf,
    const unsigned int* __restrict__ ent, const int* __restrict__ cnt,
    const float* __restrict__ be1, const float* __restrict__ We2,
    const float* __restrict__ be2, float* __restrict__ out) {
  __shared__ unsigned int pjs[8192];        // pre_j[b] bf16x2, 32 KB
  __shared__ unsigned int ent_s[4][128];
  __shared__ float pis[4][128];
  __shared__ float sred[8][128];
  __shared__ float s_s[4][128];
  __shared__ float r2[4][8][16];
  __shared__ int nn_s[4];
  int t = threadIdx.x;
  int node0 = blockIdx.x * 4;
  int b = blockIdx.x >> 5;
  const unsigned int* pjb = prejbf + b * 8192;
  for (int c = 0; c < 16; c++) pjs[c*512 + t] = pjb[c*512 + t];
  { int ii = t >> 7, f = t & 127;
    pis[ii][f] = pre_i[(node0 + ii)*128 + f] + be1[f];
    ent_s[ii][f] = ent[(node0 + ii)*128 + f]; }
  if (t < 4) nn_s[t] = cnt[node0 + t] & 0xffff;   // true neighbor count
  __syncthreads();
  int w = t >> 6, lane = t & 63;
  int ii = w >> 1, par = w & 1;
  float pia = pis[ii][2*lane];
  float pib = pis[ii][2*lane + 1];
  int nn = nn_s[ii];
  float a0 = 0.f, a1 = 0.f;
  for (int e = par; e < nn; e += 2) {
    unsigned int u = ent_s[ii][e];
    int j = u & 127;
    unsigned int hv = pjs[j*64 + lane];
    a0 += sspf(pia + bflo(hv));
    a1 += sspf(pib + bfhi(hv));
  }
  *(float2*)&sred[w][2*lane] = make_float2(a0, a1);
  __syncthreads();
  { int i2 = t >> 7, f = t & 127;
    s_s[i2][f] = sred[2*i2][f] + sred[2*i2+1][f]; }
  __syncthreads();
  { int i2 = t >> 7, o = t & 15, seg = (t >> 4) & 7;
    float p = 0.f;
    for (int f = seg*16; f < seg*16 + 16; f++) p += s_s[i2][f] * We2[f*16 + o];
    r2[i2][seg][o] = p; }
  __syncthreads();
  if (t < 64) {
    int i2 = t >> 4, o = t & 15;
    float v = be2[o] * (float)nn_s[i2];
    for (int seg = 0; seg < 8; seg++) v += r2[i2][seg][o];
    out[(node0 + i2)*16 + o] = v;
  }
}

// ---------------------------------------------------------------------------
extern "C" void kernel_launch(void* const* d_in, const int* in_sizes, int n_in,
                              void* d_out, int out_size, void* d_ws, size_t ws_size,
                              hipStream_t stream) {
  const float* coords = (const float*)d_in[0];
  const int*   species= (const int*)  d_in[1];
  const float* emb    = (const float*)d_in[2];
  const float* Wc1    = (const float*)d_in[3];
  const float* bc1    = (const float*)d_in[4];
  const float* Wc2    = (const float*)d_in[5];
  const float* bc2    = (const float*)d_in[6];
  const float* Wu1    = (const float*)d_in[7];
  const float* bu1    = (const float*)d_in[8];
  const float* Wu2    = (const float*)d_in[9];
  const float* bu2    = (const float*)d_in[10];
  const float* Wp1    = (const float*)d_in[11];
  const float* bp1    = (const float*)d_in[12];
  const float* Wp2    = (const float*)d_in[13];
  const float* bp2    = (const float*)d_in[14];
  const float* Wei    = (const float*)d_in[15];
  const float* Wej    = (const float*)d_in[16];
  const float* be1    = (const float*)d_in[17];
  const float* We2    = (const float*)d_in[18];
  const float* be2    = (const float*)d_in[19];
  float* out = (float*)d_out;

  float* wsf = (float*)d_ws;
  float*        table  = wsf;                              //  524,416
  float*        h_a    = wsf + 524416;                     //  262,144
  float*        h_b    = wsf + 786560;                     //  262,144
  float*        pre_i  = wsf + 1048704;                    //  262,144
  unsigned int* hbf_a  = (unsigned int*)(wsf + 1310848);   //  131,072
  unsigned int* hbf_b  = (unsigned int*)(wsf + 1441920);   //  131,072
  unsigned int* prejbf = (unsigned int*)(wsf + 1572992);   //  131,072
  unsigned int* ent    = (unsigned int*)(wsf + 1704064);   //  262,144
  int*          cnt    = (int*)(wsf + 1966208);            //  2,048
  (void)in_sizes; (void)n_in; (void)out_size; (void)ws_size;

  prep_kernel<<<1536, 256, 0, stream>>>(coords, Wc1, bc1, Wc2, bc2, table, ent, cnt);
  conv_t<true, false><<<512, 512, 0, stream>>>(
      nullptr, nullptr, h_b, hbf_b, species, emb, table, ent, cnt,
      Wu1, bu1, Wu2, bu2,
      nullptr, nullptr, nullptr, nullptr, nullptr, nullptr, nullptr, nullptr, nullptr);
  conv_t<false, false><<<512, 512, 0, stream>>>(
      h_b, hbf_b, h_a, hbf_a, species, emb, table, ent, cnt,
      Wu1, bu1, Wu2, bu2,
      nullptr, nullptr, nullptr, nullptr, nullptr, nullptr, nullptr, nullptr, nullptr);
  conv_t<false, true><<<512, 512, 0, stream>>>(
      h_a, hbf_a, nullptr, nullptr, species, emb, table, ent, cnt,
      Wu1, bu1, Wu2, bu2,
      Wp1, bp1, Wp2, bp2, Wei, Wej, pre_i, prejbf, out);
  edgepool_kernel<<<512, 512, 0, stream>>>(pre_i, prejbf, ent, cnt, be1, We2, be2,
                                           out + 16384);
}